// Round 11
// baseline (1264.065 us; speedup 1.0000x reference)
//
#include <hip/hip_runtime.h>
#include <hip/hip_bf16.h>

#define S_LEN 2048
#define BATCH 2
#define DIM 128
#define NH 8
#define HD 1024
#define QL 5
#define KKTOT 640   // DIM*QL
#define OCH 2048
#define MAXNNZ 384

// ---------------- transpose w_qk (O,I,T) -> (I*T, O) for coalesced GEMM reads
__global__ void k_transpose_wqk(const float* __restrict__ w, float* __restrict__ wt) {
    int i = blockIdx.x * 256 + threadIdx.x;   // i = kk*2048 + o
    if (i >= KKTOT * OCH) return;
    int kk = i >> 11;
    int o  = i & 2047;
    wt[i] = w[o * KKTOT + kk];
}

// ---------------- compact mask rows to CSR (deterministic ballot compaction)
__global__ void k_mask_csr(const float* __restrict__ mask, unsigned* __restrict__ cnt,
                           unsigned* __restrict__ idx) {
    __shared__ unsigned s_base;
    __shared__ unsigned s_wcnt[4];
    int r = blockIdx.x;
    int tid = threadIdx.x;
    int lane = tid & 63;
    int w = tid >> 6;
    if (tid == 0) s_base = 0;
    __syncthreads();
    for (int c0 = 0; c0 < S_LEN; c0 += 256) {
        int c = c0 + tid;
        bool act = mask[(size_t)r * S_LEN + c] > 0.5f;
        unsigned long long bal = __ballot(act);
        if (lane == 0) s_wcnt[w] = (unsigned)__popcll(bal);
        __syncthreads();
        unsigned off = s_base;
        for (int i = 0; i < w; i++) off += s_wcnt[i];
        off += (unsigned)__popcll(bal & ((1ull << lane) - 1ull));
        if (act && off < MAXNNZ) idx[r * MAXNNZ + off] = (unsigned)c;
        __syncthreads();
        if (tid == 0) s_base += s_wcnt[0] + s_wcnt[1] + s_wcnt[2] + s_wcnt[3];
        __syncthreads();
    }
    if (tid == 0) cnt[r] = (s_base < MAXNNZ) ? s_base : MAXNNZ;
}

// ---------------- value = x @ w_v + b_v   (B*S,128)x(128,1024)
// grid (BATCH*S/16, 4), block 256
__global__ void k_value(const float* __restrict__ x, const float* __restrict__ wv,
                        const float* __restrict__ bv, float* __restrict__ val) {
    __shared__ float xs[16][128];
    int bs0 = blockIdx.x * 16;
    int c = blockIdx.y * 256 + threadIdx.x;
    for (int t = threadIdx.x; t < 16 * 128; t += 256)
        xs[t >> 7][t & 127] = x[(size_t)(bs0 + (t >> 7)) * DIM + (t & 127)];
    __syncthreads();
    float acc[16];
#pragma unroll
    for (int r = 0; r < 16; r++) acc[r] = 0.f;
    for (int k = 0; k < 128; k += 4) {
        float w0 = wv[(k + 0) * HD + c];
        float w1 = wv[(k + 1) * HD + c];
        float w2 = wv[(k + 2) * HD + c];
        float w3 = wv[(k + 3) * HD + c];
#pragma unroll
        for (int r = 0; r < 16; r++) {
            float4 xv = *reinterpret_cast<const float4*>(&xs[r][k]);
            acc[r] += xv.x * w0 + xv.y * w1 + xv.z * w2 + xv.w * w3;
        }
    }
    float b = bv[c];
#pragma unroll
    for (int r = 0; r < 16; r++)
        val[(size_t)(bs0 + r) * HD + c] = acc[r] + b;
}

// ---------------- qk = causal_conv(x, w_qk) + b_qk  as GEMM with K=640
// grid (BATCH*S/32, 8), block 256
__global__ void k_qkconv(const float* __restrict__ x, const float* __restrict__ wt,
                         const float* __restrict__ bqk, float* __restrict__ qk) {
    __shared__ float xs[36][128];
    int bs0 = blockIdx.x * 32;
    int b = bs0 >> 11;
    int s0 = bs0 & 2047;
    int o = blockIdx.y * 256 + threadIdx.x;
    for (int t = threadIdx.x; t < 36 * 128; t += 256) {
        int rr = t >> 7, i = t & 127;
        int s = s0 - 4 + rr;
        float v = 0.f;
        if (s >= 0) v = x[((size_t)b * S_LEN + s) * DIM + i];
        xs[rr][i] = v;
    }
    __syncthreads();
    float acc[32];
    float bias = bqk[o];
#pragma unroll
    for (int r = 0; r < 32; r++) acc[r] = bias;
    for (int i = 0; i < 128; i += 2) {
        float2 xr[36];
#pragma unroll
        for (int rr = 0; rr < 36; rr++)
            xr[rr] = *reinterpret_cast<const float2*>(&xs[rr][i]);
#pragma unroll
        for (int t = 0; t < QL; t++) {
            float wA = wt[((i + 0) * QL + t) * OCH + o];
            float wB = wt[((i + 1) * QL + t) * OCH + o];
#pragma unroll
            for (int r = 0; r < 32; r++)
                acc[r] += xr[r + t].x * wA + xr[r + t].y * wB;
        }
    }
    for (int r = 0; r < 32; r++)
        qk[((size_t)bs0 + r) * OCH + o] = acc[r];
}

// ---------------- sparse attention + entmax15 (bisection), one block per (b,h,row)
__global__ void __launch_bounds__(256) k_attn(const float* __restrict__ qk,
                                              const float* __restrict__ val,
                                              const unsigned* __restrict__ cnt,
                                              const unsigned* __restrict__ idxbuf,
                                              float* __restrict__ attout) {
    __shared__ float qs[128];
    __shared__ float ssc[MAXNNZ];
    __shared__ unsigned sidx[MAXNNZ];
    __shared__ float pacc[2][128];
    int bid = blockIdx.x;
    int r = bid & (S_LEN - 1);
    int h = (bid >> 11) & (NH - 1);
    int b = bid >> 14;
    int tid = threadIdx.x;
    int lane = tid & 63;
    int wave = tid >> 6;
    int n = (int)cnt[r];
    if (tid < 128) qs[tid] = qk[((size_t)(b * S_LEN + r)) * OCH + h * 128 + tid];
    for (int j = tid; j < n; j += 256) sidx[j] = idxbuf[r * MAXNNZ + j];
    __syncthreads();
    float qr0 = qs[lane], qr1 = qs[64 + lane];
    const float scale = 0.08838834764831843f;  // 1/sqrt(128)
    for (int j = wave; j < n; j += 4) {
        const float* kp = qk + ((size_t)(b * S_LEN + (int)sidx[j])) * OCH + HD + h * 128;
        float p = qr0 * kp[lane] + qr1 * kp[64 + lane];
#pragma unroll
        for (int off = 32; off >= 1; off >>= 1) p += __shfl_xor(p, off, 64);
        if (lane == 0) ssc[j] = p * scale;
    }
    __syncthreads();
    if (wave == 0) {
        float xl[6];
        float mx = -1e30f;
#pragma unroll
        for (int l = 0; l < 6; l++) {
            int j = lane + 64 * l;
            xl[l] = (j < n) ? ssc[j] : -1e30f;
            mx = fmaxf(mx, xl[l]);
        }
#pragma unroll
        for (int off = 32; off >= 1; off >>= 1) mx = fmaxf(mx, __shfl_xor(mx, off, 64));
#pragma unroll
        for (int l = 0; l < 6; l++) xl[l] = (xl[l] - mx) * 0.5f;
        // bisection for tau: f(tau) = sum((X-tau)_+^2) = 1, root in [-1, 0]
        float lo = -1.f, hi = 0.f;
        for (int it = 0; it < 30; it++) {
            float mid = 0.5f * (lo + hi);
            float f = 0.f;
#pragma unroll
            for (int l = 0; l < 6; l++) {
                float d = fmaxf(xl[l] - mid, 0.f);
                f += d * d;
            }
#pragma unroll
            for (int off = 32; off >= 1; off >>= 1) f += __shfl_xor(f, off, 64);
            if (f > 1.f) lo = mid; else hi = mid;
        }
        float tau = 0.5f * (lo + hi);
#pragma unroll
        for (int l = 0; l < 6; l++) {
            int j = lane + 64 * l;
            if (j < n) {
                float d = fmaxf(xl[l] - tau, 0.f);
                ssc[j] = d * d;
            }
        }
    }
    __syncthreads();
    int d = tid & 127, half = tid >> 7;
    float acc = 0.f;
    for (int j = half; j < n; j += 2)
        acc += ssc[j] * val[((size_t)(b * S_LEN + (int)sidx[j])) * HD + h * 128 + d];
    pacc[half][d] = acc;
    __syncthreads();
    if (tid < 128)
        attout[((size_t)(b * S_LEN + r)) * HD + h * 128 + tid] = pacc[0][tid] + pacc[1][tid];
}

// ---------------- out = attout @ w_proj + b_proj, store FLOAT32
// grid BATCH*S/16, block 256 (2-way split-K x 128 cols)
__global__ void k_proj(const float* __restrict__ ao, const float* __restrict__ wp,
                       const float* __restrict__ bp, float* __restrict__ out) {
    __shared__ float xs[2][16][128];
    int bs0 = blockIdx.x * 16;
    int tid = threadIdx.x;
    int dout = tid & 127;
    int kh = tid >> 7;
    float acc[16];
#pragma unroll
    for (int r = 0; r < 16; r++) acc[r] = 0.f;
    for (int cc = 0; cc < 4; cc++) {
        int kb = (kh + 2 * cc) * 128;
        __syncthreads();
        for (int t = dout; t < 16 * 128; t += 128)
            xs[kh][t >> 7][t & 127] = ao[(size_t)(bs0 + (t >> 7)) * HD + kb + (t & 127)];
        __syncthreads();
        for (int k = 0; k < 128; k += 4) {
            float w0 = wp[(kb + k + 0) * DIM + dout];
            float w1 = wp[(kb + k + 1) * DIM + dout];
            float w2 = wp[(kb + k + 2) * DIM + dout];
            float w3 = wp[(kb + k + 3) * DIM + dout];
#pragma unroll
            for (int r = 0; r < 16; r++) {
                float4 xv = *reinterpret_cast<const float4*>(&xs[kh][r][k]);
                acc[r] += xv.x * w0 + xv.y * w1 + xv.z * w2 + xv.w * w3;
            }
        }
    }
    __syncthreads();
#pragma unroll
    for (int r = 0; r < 16; r++) xs[kh][r][dout] = acc[r];
    __syncthreads();
    if (kh == 0) {
        float bb = bp[dout];
        for (int r = 0; r < 16; r++)
            out[(size_t)(bs0 + r) * DIM + dout] = xs[0][r][dout] + xs[1][r][dout] + bb;
    }
}

extern "C" void kernel_launch(void* const* d_in, const int* in_sizes, int n_in,
                              void* d_out, int out_size, void* d_ws, size_t ws_size,
                              hipStream_t stream) {
    const float* x      = (const float*)d_in[0];
    const float* mask   = (const float*)d_in[1];
    const float* w_qk   = (const float*)d_in[2];
    const float* b_qk   = (const float*)d_in[3];
    const float* w_v    = (const float*)d_in[4];
    const float* b_v    = (const float*)d_in[5];
    const float* w_proj = (const float*)d_in[6];
    const float* b_proj = (const float*)d_in[7];
    float* out = (float*)d_out;     // *** reference output dtype is FLOAT32 ***

    // tight workspace packing (total 75,505,664 B ~ 72 MiB)
    char* ws = (char*)d_ws;
    float*    val  = (float*)(ws + 0);           // 16,777,216 B
    float*    qk   = (float*)(ws + 16777216);    // 33,554,432 B
    float*    wt   = (float*)(ws + 50331648);    //  5,242,880 B
    unsigned* cnt  = (unsigned*)(ws + 55574528); //      8,192 B
    unsigned* idx  = (unsigned*)(ws + 55582720); //  3,145,728 B
    float*    ao   = (float*)(ws + 58728448);    // 16,777,216 B -> end 75,505,664

    hipLaunchKernelGGL(k_transpose_wqk, dim3((KKTOT * OCH) / 256), dim3(256), 0, stream, w_qk, wt);
    hipLaunchKernelGGL(k_mask_csr, dim3(S_LEN), dim3(256), 0, stream, mask, cnt, idx);
    hipLaunchKernelGGL(k_value, dim3((BATCH * S_LEN) / 16, 4), dim3(256), 0, stream, x, w_v, b_v, val);
    hipLaunchKernelGGL(k_qkconv, dim3((BATCH * S_LEN) / 32, 8), dim3(256), 0, stream, x, wt, b_qk, qk);
    hipLaunchKernelGGL(k_attn, dim3(BATCH * NH * S_LEN), dim3(256), 0, stream, qk, val, cnt, idx, ao);
    hipLaunchKernelGGL(k_proj, dim3((BATCH * S_LEN) / 16), dim3(256), 0, stream, ao, w_proj, b_proj, out);
}

// Round 12
// 960.402 us; speedup vs baseline: 1.3162x; 1.3162x over previous
//
#include <hip/hip_runtime.h>
#include <hip/hip_bf16.h>

#define S_LEN 2048
#define BATCH 2
#define DIM 128
#define NH 8
#define HD 1024
#define QL 5
#define KKTOT 640   // DIM*QL
#define OCH 2048
#define MAXNNZ 384

// ---------------- transpose w_qk (O,I,T) -> (I*T, O) for coalesced GEMM reads
__global__ void k_transpose_wqk(const float* __restrict__ w, float* __restrict__ wt) {
    int i = blockIdx.x * 256 + threadIdx.x;   // i = kk*2048 + o
    if (i >= KKTOT * OCH) return;
    int kk = i >> 11;
    int o  = i & 2047;
    wt[i] = w[o * KKTOT + kk];
}

// ---------------- compact mask rows to CSR (deterministic ballot compaction)
__global__ void k_mask_csr(const float* __restrict__ mask, unsigned* __restrict__ cnt,
                           unsigned* __restrict__ idx) {
    __shared__ unsigned s_base;
    __shared__ unsigned s_wcnt[4];
    int r = blockIdx.x;
    int tid = threadIdx.x;
    int lane = tid & 63;
    int w = tid >> 6;
    if (tid == 0) s_base = 0;
    __syncthreads();
    for (int c0 = 0; c0 < S_LEN; c0 += 256) {
        int c = c0 + tid;
        bool act = mask[(size_t)r * S_LEN + c] > 0.5f;
        unsigned long long bal = __ballot(act);
        if (lane == 0) s_wcnt[w] = (unsigned)__popcll(bal);
        __syncthreads();
        unsigned off = s_base;
        for (int i = 0; i < w; i++) off += s_wcnt[i];
        off += (unsigned)__popcll(bal & ((1ull << lane) - 1ull));
        if (act && off < MAXNNZ) idx[r * MAXNNZ + off] = (unsigned)c;
        __syncthreads();
        if (tid == 0) s_base += s_wcnt[0] + s_wcnt[1] + s_wcnt[2] + s_wcnt[3];
        __syncthreads();
    }
    if (tid == 0) cnt[r] = (s_base < MAXNNZ) ? s_base : MAXNNZ;
}

// ---------------- value = x @ w_v + b_v   (B*S,128)x(128,1024)
// grid (BATCH*S/16, 4), block 256
__global__ void k_value(const float* __restrict__ x, const float* __restrict__ wv,
                        const float* __restrict__ bv, float* __restrict__ val) {
    __shared__ float xs[16][128];
    int bs0 = blockIdx.x * 16;
    int c = blockIdx.y * 256 + threadIdx.x;
    for (int t = threadIdx.x; t < 16 * 128; t += 256)
        xs[t >> 7][t & 127] = x[(size_t)(bs0 + (t >> 7)) * DIM + (t & 127)];
    __syncthreads();
    float acc[16];
#pragma unroll
    for (int r = 0; r < 16; r++) acc[r] = 0.f;
    for (int k = 0; k < 128; k += 4) {
        float w0 = wv[(k + 0) * HD + c];
        float w1 = wv[(k + 1) * HD + c];
        float w2 = wv[(k + 2) * HD + c];
        float w3 = wv[(k + 3) * HD + c];
#pragma unroll
        for (int r = 0; r < 16; r++) {
            float4 xv = *reinterpret_cast<const float4*>(&xs[r][k]);
            acc[r] += xv.x * w0 + xv.y * w1 + xv.z * w2 + xv.w * w3;
        }
    }
    float b = bv[c];
#pragma unroll
    for (int r = 0; r < 16; r++)
        val[(size_t)(bs0 + r) * HD + c] = acc[r] + b;
}

// ---------------- qk = causal_conv(x, w_qk) + b_qk  as GEMM with K=640
// grid (BATCH*S/32, 8), block 256
__global__ void k_qkconv(const float* __restrict__ x, const float* __restrict__ wt,
                         const float* __restrict__ bqk, float* __restrict__ qk) {
    __shared__ float xs[36][128];
    int bs0 = blockIdx.x * 32;
    int b = bs0 >> 11;
    int s0 = bs0 & 2047;
    int o = blockIdx.y * 256 + threadIdx.x;
    for (int t = threadIdx.x; t < 36 * 128; t += 256) {
        int rr = t >> 7, i = t & 127;
        int s = s0 - 4 + rr;
        float v = 0.f;
        if (s >= 0) v = x[((size_t)b * S_LEN + s) * DIM + i];
        xs[rr][i] = v;
    }
    __syncthreads();
    float acc[32];
    float bias = bqk[o];
#pragma unroll
    for (int r = 0; r < 32; r++) acc[r] = bias;
    for (int i = 0; i < 128; i += 2) {
        float2 xr[36];
#pragma unroll
        for (int rr = 0; rr < 36; rr++)
            xr[rr] = *reinterpret_cast<const float2*>(&xs[rr][i]);
#pragma unroll
        for (int t = 0; t < QL; t++) {
            float wA = wt[((i + 0) * QL + t) * OCH + o];
            float wB = wt[((i + 1) * QL + t) * OCH + o];
#pragma unroll
            for (int r = 0; r < 32; r++)
                acc[r] += xr[r + t].x * wA + xr[r + t].y * wB;
        }
    }
    for (int r = 0; r < 32; r++)
        qk[((size_t)bs0 + r) * OCH + o] = acc[r];
}

// ---------------- sparse attention + entmax15, restructured:
// QK: 4-lane groups (2-step shfl), block-wide max, tree-summed bisection.
__global__ void __launch_bounds__(256) k_attn(const float* __restrict__ qk,
                                              const float* __restrict__ val,
                                              const unsigned* __restrict__ cnt,
                                              const unsigned* __restrict__ idxbuf,
                                              float* __restrict__ attout) {
    __shared__ float qs[128];
    __shared__ float ssc[MAXNNZ];
    __shared__ unsigned sidx[MAXNNZ];
    __shared__ float pacc[2][128];
    __shared__ float red4[4];
    __shared__ float s_mx, s_tau;
    int bid = blockIdx.x;
    int r = bid & (S_LEN - 1);
    int h = (bid >> 11) & (NH - 1);
    int b = bid >> 14;
    int tid = threadIdx.x;
    int lane = tid & 63;
    int wave = tid >> 6;
    int n = (int)cnt[r];
    const float scale = 0.08838834764831843f;  // 1/sqrt(128)

    if (tid < 128) qs[tid] = qk[((size_t)(b * S_LEN + r)) * OCH + h * 128 + tid];
    for (int j = tid; j < n; j += 256) sidx[j] = idxbuf[r * MAXNNZ + j];
    __syncthreads();

    // ---- phase 1: scores, one column per 4-lane group (64 groups/block)
    {
        int grp = tid >> 2;          // 0..63
        int ll  = tid & 3;           // lane within group
        for (int j = grp; j < n; j += 64) {
            const float* kp = qk + ((size_t)(b * S_LEN + (int)sidx[j])) * OCH + HD + h * 128;
            float p = 0.f;
#pragma unroll
            for (int i = 0; i < 8; i++) {
                int m = (i * 4 + ll) << 2;                 // float4 chunk -> float offset
                float4 kv = *reinterpret_cast<const float4*>(kp + m);
                float4 qv = *reinterpret_cast<const float4*>(&qs[m]);
                p += qv.x * kv.x + qv.y * kv.y + qv.z * kv.z + qv.w * kv.w;
            }
            p += __shfl_xor(p, 1, 64);
            p += __shfl_xor(p, 2, 64);
            if (ll == 0) ssc[j] = p * scale;
        }
    }
    __syncthreads();

    // ---- phase 2a: block-wide max
    {
        float lmx = -3.0e38f;
        for (int j = tid; j < n; j += 256) lmx = fmaxf(lmx, ssc[j]);
#pragma unroll
        for (int off = 32; off >= 1; off >>= 1) lmx = fmaxf(lmx, __shfl_xor(lmx, off, 64));
        if (lane == 0) red4[wave] = lmx;
    }
    __syncthreads();
    if (tid == 0) s_mx = fmaxf(fmaxf(red4[0], red4[1]), fmaxf(red4[2], red4[3]));
    __syncthreads();
    float mx = s_mx;

    // ---- phase 2b: bisection on wave 0 (tree-summed, 26 iters)
    if (wave == 0) {
        float xl[6];
#pragma unroll
        for (int l = 0; l < 6; l++) {
            int j = lane + 64 * l;
            xl[l] = (j < n) ? (ssc[j] - mx) * 0.5f : -1.0e30f;
        }
        float lo = -1.f, hi = 0.f;
        for (int it = 0; it < 26; it++) {
            float mid = 0.5f * (lo + hi);
            float d0 = fmaxf(xl[0] - mid, 0.f), d1 = fmaxf(xl[1] - mid, 0.f);
            float d2 = fmaxf(xl[2] - mid, 0.f), d3 = fmaxf(xl[3] - mid, 0.f);
            float d4 = fmaxf(xl[4] - mid, 0.f), d5 = fmaxf(xl[5] - mid, 0.f);
            float f = ((d0 * d0 + d1 * d1) + (d2 * d2 + d3 * d3)) + (d4 * d4 + d5 * d5);
#pragma unroll
            for (int off = 32; off >= 1; off >>= 1) f += __shfl_xor(f, off, 64);
            if (f > 1.f) lo = mid; else hi = mid;
        }
        float tau = 0.5f * (lo + hi);
#pragma unroll
        for (int l = 0; l < 6; l++) {
            int j = lane + 64 * l;
            if (j < n) {
                float d = fmaxf(xl[l] - tau, 0.f);
                ssc[j] = d * d;
            }
        }
    }
    __syncthreads();

    // ---- phase 3: PV (2 halves x 128 dims)
    int d = tid & 127, half = tid >> 7;
    float acc = 0.f;
    for (int j = half; j < n; j += 2)
        acc += ssc[j] * val[((size_t)(b * S_LEN + (int)sidx[j])) * HD + h * 128 + d];
    pacc[half][d] = acc;
    __syncthreads();
    if (tid < 128)
        attout[((size_t)(b * S_LEN + r)) * HD + h * 128 + tid] = pacc[0][tid] + pacc[1][tid];
}

// ---------------- out = attout @ w_proj + b_proj, store FLOAT32
// grid BATCH*S/16, block 256 (2-way split-K x 128 cols)
__global__ void k_proj(const float* __restrict__ ao, const float* __restrict__ wp,
                       const float* __restrict__ bp, float* __restrict__ out) {
    __shared__ float xs[2][16][128];
    int bs0 = blockIdx.x * 16;
    int tid = threadIdx.x;
    int dout = tid & 127;
    int kh = tid >> 7;
    float acc[16];
#pragma unroll
    for (int r = 0; r < 16; r++) acc[r] = 0.f;
    for (int cc = 0; cc < 4; cc++) {
        int kb = (kh + 2 * cc) * 128;
        __syncthreads();
        for (int t = dout; t < 16 * 128; t += 128)
            xs[kh][t >> 7][t & 127] = ao[(size_t)(bs0 + (t >> 7)) * HD + kb + (t & 127)];
        __syncthreads();
        for (int k = 0; k < 128; k += 4) {
            float w0 = wp[(kb + k + 0) * DIM + dout];
            float w1 = wp[(kb + k + 1) * DIM + dout];
            float w2 = wp[(kb + k + 2) * DIM + dout];
            float w3 = wp[(kb + k + 3) * DIM + dout];
#pragma unroll
            for (int r = 0; r < 16; r++) {
                float4 xv = *reinterpret_cast<const float4*>(&xs[kh][r][k]);
                acc[r] += xv.x * w0 + xv.y * w1 + xv.z * w2 + xv.w * w3;
            }
        }
    }
    __syncthreads();
#pragma unroll
    for (int r = 0; r < 16; r++) xs[kh][r][dout] = acc[r];
    __syncthreads();
    if (kh == 0) {
        float bb = bp[dout];
        for (int r = 0; r < 16; r++)
            out[(size_t)(bs0 + r) * DIM + dout] = xs[0][r][dout] + xs[1][r][dout] + bb;
    }
}

extern "C" void kernel_launch(void* const* d_in, const int* in_sizes, int n_in,
                              void* d_out, int out_size, void* d_ws, size_t ws_size,
                              hipStream_t stream) {
    const float* x      = (const float*)d_in[0];
    const float* mask   = (const float*)d_in[1];
    const float* w_qk   = (const float*)d_in[2];
    const float* b_qk   = (const float*)d_in[3];
    const float* w_v    = (const float*)d_in[4];
    const float* b_v    = (const float*)d_in[5];
    const float* w_proj = (const float*)d_in[6];
    const float* b_proj = (const float*)d_in[7];
    float* out = (float*)d_out;     // reference output dtype is FLOAT32

    // tight workspace packing (total 75,505,664 B ~ 72 MiB)
    char* ws = (char*)d_ws;
    float*    val  = (float*)(ws + 0);           // 16,777,216 B
    float*    qk   = (float*)(ws + 16777216);    // 33,554,432 B
    float*    wt   = (float*)(ws + 50331648);    //  5,242,880 B
    unsigned* cnt  = (unsigned*)(ws + 55574528); //      8,192 B
    unsigned* idx  = (unsigned*)(ws + 55582720); //  3,145,728 B
    float*    ao   = (float*)(ws + 58728448);    // 16,777,216 B -> end 75,505,664

    hipLaunchKernelGGL(k_transpose_wqk, dim3((KKTOT * OCH) / 256), dim3(256), 0, stream, w_qk, wt);
    hipLaunchKernelGGL(k_mask_csr, dim3(S_LEN), dim3(256), 0, stream, mask, cnt, idx);
    hipLaunchKernelGGL(k_value, dim3((BATCH * S_LEN) / 16, 4), dim3(256), 0, stream, x, w_v, b_v, val);
    hipLaunchKernelGGL(k_qkconv, dim3((BATCH * S_LEN) / 32, 8), dim3(256), 0, stream, x, wt, b_qk, qk);
    hipLaunchKernelGGL(k_attn, dim3(BATCH * NH * S_LEN), dim3(256), 0, stream, qk, val, cnt, idx, ao);
    hipLaunchKernelGGL(k_proj, dim3((BATCH * S_LEN) / 16), dim3(256), 0, stream, ao, w_proj, b_proj, out);
}

// Round 13
// 689.182 us; speedup vs baseline: 1.8342x; 1.3935x over previous
//
#include <hip/hip_runtime.h>
#include <hip/hip_bf16.h>

#define S_LEN 2048
#define BATCH 2
#define DIM 128
#define NH 8
#define HD 1024
#define QL 5
#define KKTOT 640   // DIM*QL
#define OCH 2048
#define MAXNNZ 384

// ---------------- transpose w_qk (O,I,T) -> (I*T, O) for coalesced GEMM reads
__global__ void k_transpose_wqk(const float* __restrict__ w, float* __restrict__ wt) {
    int i = blockIdx.x * 256 + threadIdx.x;   // i = kk*2048 + o
    if (i >= KKTOT * OCH) return;
    int kk = i >> 11;
    int o  = i & 2047;
    wt[i] = w[o * KKTOT + kk];
}

// ---------------- compact mask rows to CSR (deterministic ballot compaction)
__global__ void k_mask_csr(const float* __restrict__ mask, unsigned* __restrict__ cnt,
                           unsigned* __restrict__ idx) {
    __shared__ unsigned s_base;
    __shared__ unsigned s_wcnt[4];
    int r = blockIdx.x;
    int tid = threadIdx.x;
    int lane = tid & 63;
    int w = tid >> 6;
    if (tid == 0) s_base = 0;
    __syncthreads();
    for (int c0 = 0; c0 < S_LEN; c0 += 256) {
        int c = c0 + tid;
        bool act = mask[(size_t)r * S_LEN + c] > 0.5f;
        unsigned long long bal = __ballot(act);
        if (lane == 0) s_wcnt[w] = (unsigned)__popcll(bal);
        __syncthreads();
        unsigned off = s_base;
        for (int i = 0; i < w; i++) off += s_wcnt[i];
        off += (unsigned)__popcll(bal & ((1ull << lane) - 1ull));
        if (act && off < MAXNNZ) idx[r * MAXNNZ + off] = (unsigned)c;
        __syncthreads();
        if (tid == 0) s_base += s_wcnt[0] + s_wcnt[1] + s_wcnt[2] + s_wcnt[3];
        __syncthreads();
    }
    if (tid == 0) cnt[r] = (s_base < MAXNNZ) ? s_base : MAXNNZ;
}

// ---------------- value = x @ w_v + b_v   (B*S,128)x(128,1024)
// grid (BATCH*S/16, 4), block 256
__global__ void k_value(const float* __restrict__ x, const float* __restrict__ wv,
                        const float* __restrict__ bv, float* __restrict__ val) {
    __shared__ float xs[16][128];
    int bs0 = blockIdx.x * 16;
    int c = blockIdx.y * 256 + threadIdx.x;
    for (int t = threadIdx.x; t < 16 * 128; t += 256)
        xs[t >> 7][t & 127] = x[(size_t)(bs0 + (t >> 7)) * DIM + (t & 127)];
    __syncthreads();
    float acc[16];
#pragma unroll
    for (int r = 0; r < 16; r++) acc[r] = 0.f;
    for (int k = 0; k < 128; k += 4) {
        float w0 = wv[(k + 0) * HD + c];
        float w1 = wv[(k + 1) * HD + c];
        float w2 = wv[(k + 2) * HD + c];
        float w3 = wv[(k + 3) * HD + c];
#pragma unroll
        for (int r = 0; r < 16; r++) {
            float4 xv = *reinterpret_cast<const float4*>(&xs[r][k]);
            acc[r] += xv.x * w0 + xv.y * w1 + xv.z * w2 + xv.w * w3;
        }
    }
    float b = bv[c];
#pragma unroll
    for (int r = 0; r < 16; r++)
        val[(size_t)(bs0 + r) * HD + c] = acc[r] + b;
}

// ---------------- qk = causal_conv(x, w_qk) + b_qk  as GEMM with K=640
// grid (BATCH*S/32, 8), block 256
__global__ void k_qkconv(const float* __restrict__ x, const float* __restrict__ wt,
                         const float* __restrict__ bqk, float* __restrict__ qk) {
    __shared__ float xs[36][128];
    int bs0 = blockIdx.x * 32;
    int b = bs0 >> 11;
    int s0 = bs0 & 2047;
    int o = blockIdx.y * 256 + threadIdx.x;
    for (int t = threadIdx.x; t < 36 * 128; t += 256) {
        int rr = t >> 7, i = t & 127;
        int s = s0 - 4 + rr;
        float v = 0.f;
        if (s >= 0) v = x[((size_t)b * S_LEN + s) * DIM + i];
        xs[rr][i] = v;
    }
    __syncthreads();
    float acc[32];
    float bias = bqk[o];
#pragma unroll
    for (int r = 0; r < 32; r++) acc[r] = bias;
    for (int i = 0; i < 128; i += 2) {
        float2 xr[36];
#pragma unroll
        for (int rr = 0; rr < 36; rr++)
            xr[rr] = *reinterpret_cast<const float2*>(&xs[rr][i]);
#pragma unroll
        for (int t = 0; t < QL; t++) {
            float wA = wt[((i + 0) * QL + t) * OCH + o];
            float wB = wt[((i + 1) * QL + t) * OCH + o];
#pragma unroll
            for (int r = 0; r < 32; r++)
                acc[r] += xr[r + t].x * wA + xr[r + t].y * wB;
        }
    }
    for (int r = 0; r < 32; r++)
        qk[((size_t)bs0 + r) * OCH + o] = acc[r];
}

// ---------------- sparse attention + entmax15
// QK: 4-lane groups; bisection on wave 0; PV: 8 col-slots x 32 float4 dims.
__global__ void __launch_bounds__(256) k_attn(const float* __restrict__ qk,
                                              const float* __restrict__ val,
                                              const unsigned* __restrict__ cnt,
                                              const unsigned* __restrict__ idxbuf,
                                              float* __restrict__ attout) {
    __shared__ float qs[128];
    __shared__ float ssc[MAXNNZ];
    __shared__ unsigned sidx[MAXNNZ];
    __shared__ float4 pv4[8][32];
    __shared__ float red4[4];
    __shared__ float s_mx;
    int bid = blockIdx.x;
    int r = bid & (S_LEN - 1);
    int h = (bid >> 11) & (NH - 1);
    int b = bid >> 14;
    int tid = threadIdx.x;
    int lane = tid & 63;
    int wave = tid >> 6;
    int n = (int)cnt[r];
    const float scale = 0.08838834764831843f;  // 1/sqrt(128)

    if (tid < 128) qs[tid] = qk[((size_t)(b * S_LEN + r)) * OCH + h * 128 + tid];
    for (int j = tid; j < n; j += 256) sidx[j] = idxbuf[r * MAXNNZ + j];
    __syncthreads();

    // ---- phase 1: scores, one column per 4-lane group (64 groups/block)
    {
        int grp = tid >> 2;          // 0..63
        int ll  = tid & 3;           // lane within group
        const float* kbase = qk + (size_t)b * S_LEN * OCH + HD + h * 128;
        for (int j = grp; j < n; j += 64) {
            const float* kp = kbase + ((size_t)sidx[j]) * OCH;
            float p = 0.f;
#pragma unroll
            for (int i = 0; i < 8; i++) {
                int m = (i * 4 + ll) << 2;                 // float4 chunk -> float offset
                float4 kv = *reinterpret_cast<const float4*>(kp + m);
                float4 qv = *reinterpret_cast<const float4*>(&qs[m]);
                p += qv.x * kv.x + qv.y * kv.y + qv.z * kv.z + qv.w * kv.w;
            }
            p += __shfl_xor(p, 1, 64);
            p += __shfl_xor(p, 2, 64);
            if (ll == 0) ssc[j] = p * scale;
        }
    }
    __syncthreads();

    // ---- phase 2a: block-wide max
    {
        float lmx = -3.0e38f;
        for (int j = tid; j < n; j += 256) lmx = fmaxf(lmx, ssc[j]);
#pragma unroll
        for (int off = 32; off >= 1; off >>= 1) lmx = fmaxf(lmx, __shfl_xor(lmx, off, 64));
        if (lane == 0) red4[wave] = lmx;
    }
    __syncthreads();
    if (tid == 0) s_mx = fmaxf(fmaxf(red4[0], red4[1]), fmaxf(red4[2], red4[3]));
    __syncthreads();
    float mx = s_mx;

    // ---- phase 2b: bisection on wave 0 (tree-summed, 26 iters), weights -> ssc
    if (wave == 0) {
        float xl[6];
#pragma unroll
        for (int l = 0; l < 6; l++) {
            int j = lane + 64 * l;
            xl[l] = (j < n) ? (ssc[j] - mx) * 0.5f : -1.0e30f;
        }
        float lo = -1.f, hi = 0.f;
        for (int it = 0; it < 26; it++) {
            float mid = 0.5f * (lo + hi);
            float d0 = fmaxf(xl[0] - mid, 0.f), d1 = fmaxf(xl[1] - mid, 0.f);
            float d2 = fmaxf(xl[2] - mid, 0.f), d3 = fmaxf(xl[3] - mid, 0.f);
            float d4 = fmaxf(xl[4] - mid, 0.f), d5 = fmaxf(xl[5] - mid, 0.f);
            float f = ((d0 * d0 + d1 * d1) + (d2 * d2 + d3 * d3)) + (d4 * d4 + d5 * d5);
#pragma unroll
            for (int off = 32; off >= 1; off >>= 1) f += __shfl_xor(f, off, 64);
            if (f > 1.f) lo = mid; else hi = mid;
        }
        float tau = 0.5f * (lo + hi);
#pragma unroll
        for (int l = 0; l < 6; l++) {
            int j = lane + 64 * l;
            if (j < n) {
                float d = fmaxf(xl[l] - tau, 0.f);
                ssc[j] = d * d;
            }
        }
    }
    __syncthreads();

    // ---- phase 3: PV, vectorized — 8 column-slots x 32 float4 dim-groups
    {
        int slot = tid >> 5;         // 0..7
        int dg   = tid & 31;         // float4 dim group 0..31
        const float4* vbase = reinterpret_cast<const float4*>(
                                  val + (size_t)b * S_LEN * HD + h * 128) + dg;
        float4 acc = {0.f, 0.f, 0.f, 0.f};
        for (int j = slot; j < n; j += 8) {
            float w = ssc[j];
            float4 v = vbase[(size_t)sidx[j] << 8];     // c * HD/4 float4s
            acc.x += w * v.x; acc.y += w * v.y; acc.z += w * v.z; acc.w += w * v.w;
        }
        pv4[slot][dg] = acc;
    }
    __syncthreads();
    if (tid < 128) {
        int d4 = tid >> 2, comp = tid & 3;
        float a = 0.f;
#pragma unroll
        for (int s = 0; s < 8; s++) a += reinterpret_cast<const float*>(&pv4[s][d4])[comp];
        attout[((size_t)(b * S_LEN + r)) * HD + h * 128 + tid] = a;
    }
}

// ---------------- out = attout @ w_proj + b_proj, store FLOAT32
// grid BATCH*S/16, block 256 (2-way split-K x 128 cols)
__global__ void k_proj(const float* __restrict__ ao, const float* __restrict__ wp,
                       const float* __restrict__ bp, float* __restrict__ out) {
    __shared__ float xs[2][16][128];
    int bs0 = blockIdx.x * 16;
    int tid = threadIdx.x;
    int dout = tid & 127;
    int kh = tid >> 7;
    float acc[16];
#pragma unroll
    for (int r = 0; r < 16; r++) acc[r] = 0.f;
    for (int cc = 0; cc < 4; cc++) {
        int kb = (kh + 2 * cc) * 128;
        __syncthreads();
        for (int t = dout; t < 16 * 128; t += 128)
            xs[kh][t >> 7][t & 127] = ao[(size_t)(bs0 + (t >> 7)) * HD + kb + (t & 127)];
        __syncthreads();
        for (int k = 0; k < 128; k += 4) {
            float w0 = wp[(kb + k + 0) * DIM + dout];
            float w1 = wp[(kb + k + 1) * DIM + dout];
            float w2 = wp[(kb + k + 2) * DIM + dout];
            float w3 = wp[(kb + k + 3) * DIM + dout];
#pragma unroll
            for (int r = 0; r < 16; r++) {
                float4 xv = *reinterpret_cast<const float4*>(&xs[kh][r][k]);
                acc[r] += xv.x * w0 + xv.y * w1 + xv.z * w2 + xv.w * w3;
            }
        }
    }
    __syncthreads();
#pragma unroll
    for (int r = 0; r < 16; r++) xs[kh][r][dout] = acc[r];
    __syncthreads();
    if (kh == 0) {
        float bb = bp[dout];
        for (int r = 0; r < 16; r++)
            out[(size_t)(bs0 + r) * DIM + dout] = xs[0][r][dout] + xs[1][r][dout] + bb;
    }
}

extern "C" void kernel_launch(void* const* d_in, const int* in_sizes, int n_in,
                              void* d_out, int out_size, void* d_ws, size_t ws_size,
                              hipStream_t stream) {
    const float* x      = (const float*)d_in[0];
    const float* mask   = (const float*)d_in[1];
    const float* w_qk   = (const float*)d_in[2];
    const float* b_qk   = (const float*)d_in[3];
    const float* w_v    = (const float*)d_in[4];
    const float* b_v    = (const float*)d_in[5];
    const float* w_proj = (const float*)d_in[6];
    const float* b_proj = (const float*)d_in[7];
    float* out = (float*)d_out;     // reference output dtype is FLOAT32

    // tight workspace packing (total 75,505,664 B ~ 72 MiB)
    char* ws = (char*)d_ws;
    float*    val  = (float*)(ws + 0);           // 16,777,216 B
    float*    qk   = (float*)(ws + 16777216);    // 33,554,432 B
    float*    wt   = (float*)(ws + 50331648);    //  5,242,880 B
    unsigned* cnt  = (unsigned*)(ws + 55574528); //      8,192 B
    unsigned* idx  = (unsigned*)(ws + 55582720); //  3,145,728 B
    float*    ao   = (float*)(ws + 58728448);    // 16,777,216 B -> end 75,505,664

    hipLaunchKernelGGL(k_transpose_wqk, dim3((KKTOT * OCH) / 256), dim3(256), 0, stream, w_qk, wt);
    hipLaunchKernelGGL(k_mask_csr, dim3(S_LEN), dim3(256), 0, stream, mask, cnt, idx);
    hipLaunchKernelGGL(k_value, dim3((BATCH * S_LEN) / 16, 4), dim3(256), 0, stream, x, w_v, b_v, val);
    hipLaunchKernelGGL(k_qkconv, dim3((BATCH * S_LEN) / 32, 8), dim3(256), 0, stream, x, wt, b_qk, qk);
    hipLaunchKernelGGL(k_attn, dim3(BATCH * NH * S_LEN), dim3(256), 0, stream, qk, val, cnt, idx, ao);
    hipLaunchKernelGGL(k_proj, dim3((BATCH * S_LEN) / 16), dim3(256), 0, stream, ao, w_proj, b_proj, out);
}